// Round 6
// baseline (742.019 us; speedup 1.0000x reference)
//
#include <hip/hip_runtime.h>
#include <hip/hip_bf16.h>

// QuantizedSimpleSSM — round 6: LDS-return-path fix. Per-thread tile 16x8
// (2x8 t-groups x 2x4 o-groups), T=128, tile 128x128 -> LDS bytes/FMA drops
// 1.0 -> 0.75. Prefetch next staging tile right after the compute barrier so
// its vmcnt drain lands one full compute phase later. All LDS access <=2-way.
// Numerics contract (absmax 0.0 since R2): every output element is one fp32
// FMA chain in strictly ascending k; recurrence mul-then-add + q8. The
// thread<->element mapping changed; per-element arithmetic did not.

#define DINX 512
#define LSEQ 512
#define NDIM 512

__device__ __forceinline__ float q8(float x) {
    float xa = fabsf(x);
    float w  = __fadd_rn(xa, 1e-8f);
    int e = (int)((__float_as_uint(w) >> 23) & 0xFFu) - 127;   // floor(log2(w))
    e = e < -7 ? -7 : (e > 7 ? 7 : e);
    float p    = __int_as_float((unsigned)((e + 127) << 23));   // exact 2^e
    float invp = __int_as_float((unsigned)((127 - e) << 23));   // exact 2^-e
    float t  = __fmul_rn(__fsub_rn(__fmul_rn(xa, invp), 1.0f), 8.0f);
    float m  = __fmul_rn(rintf(t), 0.125f);                     // half-to-even
    float r  = __fmul_rn(__fadd_rn(1.0f, m), p);
    return copysignf(r, x);
}

__global__ void quantk(const float* __restrict__ in, float* __restrict__ out, int n) {
    int i = blockIdx.x * blockDim.x + threadIdx.x;
    if (i < n) out[i] = q8(in[i]);
}

// out[c][r] = q8(in[r][c]) for three 512x512 matrices. grid (16,16,3), block 256.
__global__ __launch_bounds__(256) void quantT3(const float* __restrict__ B,
                                               const float* __restrict__ C,
                                               const float* __restrict__ D,
                                               float* __restrict__ Bqt,
                                               float* __restrict__ Cqt,
                                               float* __restrict__ Dqt) {
    __shared__ float tl[32][33];
    const float* in = blockIdx.z == 0 ? B : (blockIdx.z == 1 ? C : D);
    float* out      = blockIdx.z == 0 ? Bqt : (blockIdx.z == 1 ? Cqt : Dqt);
    const int r0 = blockIdx.y * 32, c0 = blockIdx.x * 32;
    const int x = threadIdx.x & 31, y = threadIdx.x >> 5;   // 32 x 8
#pragma unroll
    for (int i = 0; i < 32; i += 8)
        tl[y + i][x] = q8(in[(r0 + y + i) * 512 + c0 + x]);
    __syncthreads();
#pragma unroll
    for (int i = 0; i < 32; i += 8)
        out[(c0 + y + i) * 512 + r0 + x] = tl[x][y + i];
}

// acc[p][i][q][j] += sum_k X[k][m0 + p*64 + tx*8 + i] * W[k][n0 + q*64 + ty*4 + j]
// with k strictly ascending; tx=tid&7, ty=tid>>3; i<8, j<4. T=128 threads.
// X, W are [KTOT][512] row-major. Xs/Ws are [16][128] single-buffered; two
// barriers per tile; next tile's global loads issued just after the second
// barrier so they drain (vmcnt) at the *next* tile's first barrier.
__device__ __forceinline__ void gemm_pass(const float* __restrict__ X,
                                          const float* __restrict__ W,
                                          int m0, int n0, int KTOT,
                                          float (&acc)[2][8][2][4],
                                          float (*Xs)[128], float (*Ws)[128],
                                          int tid) {
    const int tx = tid & 7, ty = tid >> 3;
    const int srow = tid >> 3, scol = (tid & 7) * 4;   // staging: k-row, col base
    const float* xp = X + (size_t)srow * 512 + m0 + scol;
    const float* wp = W + (size_t)srow * 512 + n0 + scol;
    float4 px[4], pw[4];
#pragma unroll
    for (int j = 0; j < 4; ++j) {
        px[j] = *(const float4*)(xp + j * 32);
        pw[j] = *(const float4*)(wp + j * 32);
    }
    const int NT = KTOT / 16;
    for (int t = 0; t < NT; ++t) {
        __syncthreads();                 // prev compute done reading LDS
#pragma unroll
        for (int j = 0; j < 4; ++j) {
            *(float4*)&Xs[srow][scol + j * 32] = px[j];
            *(float4*)&Ws[srow][scol + j * 32] = pw[j];
        }
        __syncthreads();
        if (t + 1 < NT) {                // wave-uniform guard
            const float* xn = xp + (size_t)(t + 1) * 16 * 512;
            const float* wn = wp + (size_t)(t + 1) * 16 * 512;
#pragma unroll
            for (int j = 0; j < 4; ++j) {
                px[j] = *(const float4*)(xn + j * 32);
                pw[j] = *(const float4*)(wn + j * 32);
            }
        }
#pragma unroll
        for (int k = 0; k < 16; ++k) {
            float a[2][8], b[2][4];
            *(float4*)&a[0][0] = *(const float4*)&Xs[k][tx * 8];
            *(float4*)&a[0][4] = *(const float4*)&Xs[k][tx * 8 + 4];
            *(float4*)&a[1][0] = *(const float4*)&Xs[k][64 + tx * 8];
            *(float4*)&a[1][4] = *(const float4*)&Xs[k][64 + tx * 8 + 4];
            *(float4*)&b[0][0] = *(const float4*)&Ws[k][ty * 4];
            *(float4*)&b[1][0] = *(const float4*)&Ws[k][64 + ty * 4];
#pragma unroll
            for (int p = 0; p < 2; ++p)
#pragma unroll
                for (int i = 0; i < 8; ++i)
#pragma unroll
                    for (int q = 0; q < 2; ++q)
#pragma unroll
                        for (int j = 0; j < 4; ++j)
                            acc[p][i][q][j] = fmaf(a[p][i], b[q][j], acc[p][i][q][j]);
        }
    }
}

// R[b][t][n] = sum_d u[b][d][t] * Bqt[d][n]. grid (4,4,32), block 128.
__global__ __launch_bounds__(128, 1) void gemm_R(const float* __restrict__ u,
                                                 const float* __restrict__ Bqt,
                                                 float* __restrict__ R) {
    __shared__ float Xs[16][128];
    __shared__ float Ws[16][128];
    const int b  = blockIdx.z;
    const int t0 = blockIdx.x * 128, n0 = blockIdx.y * 128;
    const int tid = threadIdx.x;
    const int tx = tid & 7, ty = tid >> 3;
    const float* ub = u + (size_t)b * (DINX * LSEQ);
    float acc[2][8][2][4] = {};
    gemm_pass(ub, Bqt, t0, n0, DINX, acc, Xs, Ws, tid);
    float* Rb = R + (size_t)b * (LSEQ * NDIM);
#pragma unroll
    for (int p = 0; p < 2; ++p)
#pragma unroll
        for (int i = 0; i < 8; ++i) {
            float* row = Rb + (size_t)(t0 + p * 64 + tx * 8 + i) * NDIM + n0;
            *(float4*)(row + ty * 4)      = make_float4(acc[p][i][0][0], acc[p][i][0][1],
                                                        acc[p][i][0][2], acc[p][i][0][3]);
            *(float4*)(row + 64 + ty * 4) = make_float4(acc[p][i][1][0], acc[p][i][1][1],
                                                        acc[p][i][1][2], acc[p][i][1][3]);
        }
}

// Per-(b, n-chunk) recurrence (bitwise np: mul-then-add, q8). Writes S[b][n][t].
// grid (32, 4), block 128 (thread = one n within the chunk).
__global__ __launch_bounds__(128) void recur(const float* __restrict__ R,
                                             const float* __restrict__ Aq,
                                             float* __restrict__ S) {
    __shared__ float tile[16][132];
    const int b  = blockIdx.x;
    const int n0 = blockIdx.y * 128;
    const int n  = threadIdx.x;                 // 0..127
    const float a = Aq[n0 + n];
    const float* Rb = R + (size_t)b * (LSEQ * NDIM) + n0;
    float* Sb = S + (size_t)b * (NDIM * LSEQ) + (size_t)n0 * LSEQ;
    float s = 0.0f;
    const int c = (n & 3) * 4;
    const int rbase = n >> 2;                   // 0..31
    for (int t0 = 0; t0 < LSEQ; t0 += 16) {
#pragma unroll
        for (int tt = 0; tt < 16; ++tt) {
            float r = Rb[(size_t)(t0 + tt) * NDIM + n];
            s = q8(__fadd_rn(__fmul_rn(s, a), r));
            tile[tt][n] = s;
        }
        __syncthreads();
#pragma unroll
        for (int p = 0; p < 4; ++p) {
            int row = p * 32 + rbase;
            float4 v = make_float4(tile[c + 0][row], tile[c + 1][row],
                                   tile[c + 2][row], tile[c + 3][row]);
            *(float4*)(Sb + (size_t)row * LSEQ + t0 + c) = v;
        }
        __syncthreads();
    }
}

// Y[b][o][t] = q8( (sum_n S[n][t]*Cqt[n][o]) + (sum_d u[d][t]*Dqt[d][o]) )
__global__ __launch_bounds__(128, 1) void gemm_Y(const float* __restrict__ u,
                                                 const float* __restrict__ S,
                                                 const float* __restrict__ Cqt,
                                                 const float* __restrict__ Dqt,
                                                 float* __restrict__ Y) {
    __shared__ float Xs[16][128];
    __shared__ float Ws[16][128];
    const int b  = blockIdx.z;
    const int t0 = blockIdx.x * 128, o0 = blockIdx.y * 128;
    const int tid = threadIdx.x;
    const int tx = tid & 7, ty = tid >> 3;
    const float* Sb = S + (size_t)b * (NDIM * LSEQ);
    const float* ub = u + (size_t)b * (DINX * LSEQ);
    float acc[2][8][2][4] = {};
    float c1[2][8][2][4];
    gemm_pass(Sb, Cqt, t0, o0, NDIM, acc, Xs, Ws, tid);
#pragma unroll
    for (int p = 0; p < 2; ++p)
#pragma unroll
        for (int i = 0; i < 8; ++i)
#pragma unroll
            for (int q = 0; q < 2; ++q)
#pragma unroll
                for (int j = 0; j < 4; ++j) {
                    c1[p][i][q][j] = acc[p][i][q][j];
                    acc[p][i][q][j] = 0.0f;
                }
    gemm_pass(ub, Dqt, t0, o0, DINX, acc, Xs, Ws, tid);

    float* Yb = Y + (size_t)b * (NDIM * LSEQ);
#pragma unroll
    for (int q = 0; q < 2; ++q)
#pragma unroll
        for (int j = 0; j < 4; ++j) {
            float* row = Yb + (size_t)(o0 + q * 64 + ty * 4 + j) * LSEQ + t0;
#pragma unroll
            for (int p = 0; p < 2; ++p) {
                float y[8];
#pragma unroll
                for (int i = 0; i < 8; ++i)
                    y[i] = q8(__fadd_rn(c1[p][i][q][j], acc[p][i][q][j]));
                *(float4*)(row + p * 64 + tx * 8)     = make_float4(y[0], y[1], y[2], y[3]);
                *(float4*)(row + p * 64 + tx * 8 + 4) = make_float4(y[4], y[5], y[6], y[7]);
            }
        }
}

extern "C" void kernel_launch(void* const* d_in, const int* in_sizes, int n_in,
                              void* d_out, int out_size, void* d_ws, size_t ws_size,
                              hipStream_t stream) {
    const float* u = (const float*)d_in[0];   // (32, 512, 512)
    const float* A = (const float*)d_in[1];   // (512,)
    const float* B = (const float*)d_in[2];   // (512, 512)
    const float* C = (const float*)d_in[3];   // (512, 512)
    const float* D = (const float*)d_in[4];   // (512, 512)

    float* ws  = (float*)d_ws;
    float* Aq  = ws;                    // 512
    float* Bqt = Aq + 512;              // 262144  [d][n]
    float* Cqt = Bqt + 262144;          // 262144  [n][o]
    float* Dqt = Cqt + 262144;          // 262144  [d][o]
    float* R   = Dqt + 262144;          // 8388608 [b][t][n]
    float* S   = R + 8388608;           // 8388608 [b][n][t]
    float* Y   = (float*)d_out;         // 8388608 [b][o][t]

    quantk<<<2, 256, 0, stream>>>(A, Aq, 512);
    quantT3<<<dim3(16, 16, 3), 256, 0, stream>>>(B, C, D, Bqt, Cqt, Dqt);

    gemm_R<<<dim3(4, 4, 32), 128, 0, stream>>>(u, Bqt, R);
    recur<<<dim3(32, 4), 128, 0, stream>>>(R, Aq, S);
    gemm_Y<<<dim3(4, 4, 32), 128, 0, stream>>>(u, S, Cqt, Dqt, Y);
}

// Round 7
// 490.937 us; speedup vs baseline: 1.5114x; 1.5114x over previous
//
#include <hip/hip_runtime.h>
#include <hip/hip_bf16.h>

// QuantizedSimpleSSM — round 7: SGPR-operand GEMM. Each wave owns a 16-wide
// n-strip; W[k][n] is wave-uniform -> scalar loads (s_load) + v_fma with SGPR
// src. X (t-dim) is the only LDS operand: mr=2 per lane (ds_read_b64) for
// 32 FMAs/k. Block 256 (4 waves), tile 128x64, grid 1024 = 4 blocks/CU,
// ~16 waves/CU. R stored as R'[b][n][t] -> coalesced stores, transpose-free
// recurrence.
// Numerics contract (absmax 0.0 since R2): every output element is one fp32
// FMA chain in strictly ascending k; recurrence mul-then-add + q8. Unchanged.

#define FULL 512

__device__ __forceinline__ float q8(float x) {
    float xa = fabsf(x);
    float w  = __fadd_rn(xa, 1e-8f);
    int e = (int)((__float_as_uint(w) >> 23) & 0xFFu) - 127;   // floor(log2(w))
    e = e < -7 ? -7 : (e > 7 ? 7 : e);
    float p    = __int_as_float((unsigned)((e + 127) << 23));   // exact 2^e
    float invp = __int_as_float((unsigned)((127 - e) << 23));   // exact 2^-e
    float t  = __fmul_rn(__fsub_rn(__fmul_rn(xa, invp), 1.0f), 8.0f);
    float m  = __fmul_rn(rintf(t), 0.125f);                     // half-to-even
    float r  = __fmul_rn(__fadd_rn(1.0f, m), p);
    return copysignf(r, x);
}

__global__ void quantk(const float* __restrict__ in, float* __restrict__ out, int n) {
    int i = blockIdx.x * blockDim.x + threadIdx.x;
    if (i < n) out[i] = q8(in[i]);
}

// out[c][r] = q8(in[r][c]) for three 512x512 matrices. grid (16,16,3), block 256.
__global__ __launch_bounds__(256) void quantT3(const float* __restrict__ B,
                                               const float* __restrict__ C,
                                               const float* __restrict__ D,
                                               float* __restrict__ Bqt,
                                               float* __restrict__ Cqt,
                                               float* __restrict__ Dqt) {
    __shared__ float tl[32][33];
    const float* in = blockIdx.z == 0 ? B : (blockIdx.z == 1 ? C : D);
    float* out      = blockIdx.z == 0 ? Bqt : (blockIdx.z == 1 ? Cqt : Dqt);
    const int r0 = blockIdx.y * 32, c0 = blockIdx.x * 32;
    const int x = threadIdx.x & 31, y = threadIdx.x >> 5;   // 32 x 8
#pragma unroll
    for (int i = 0; i < 32; i += 8)
        tl[y + i][x] = q8(in[(r0 + y + i) * FULL + c0 + x]);
    __syncthreads();
#pragma unroll
    for (int i = 0; i < 32; i += 8)
        out[(c0 + y + i) * FULL + r0 + x] = tl[x][y + i];
}

// acc0[j]/acc1[j] accumulate Out[m0+lane*2 + {0,1}][nw0+j] += X[k][m]*Wt[k][n],
// k strictly ascending. X, Wt are [512][512] row-major. nw0 MUST be
// wave-uniform (readfirstlane-derived) so Wt reads become scalar loads.
__device__ __forceinline__ void gemm_pass_sgpr(const float* __restrict__ X,
                                               const float* __restrict__ Wt,
                                               int m0, int nw0,
                                               float (&acc0)[16], float (&acc1)[16],
                                               float (*Xs)[128],
                                               int tid, int lane) {
    const int row = tid >> 4, col = (tid & 15) * 8;   // staging: 16 x (16x8)
    const float* xp = X + (size_t)row * FULL + m0 + col;
    for (int k0 = 0; k0 < FULL; k0 += 16) {
        float4 x0 = *(const float4*)(xp);
        float4 x1 = *(const float4*)(xp + 4);
        xp += 16 * FULL;
        __syncthreads();                 // prev compute done reading Xs
        *(float4*)&Xs[row][col]     = x0;
        *(float4*)&Xs[row][col + 4] = x1;
        __syncthreads();
        const float* wb = Wt + (size_t)k0 * FULL + nw0;   // uniform
#pragma unroll
        for (int k = 0; k < 16; ++k) {
            float2 a = *(const float2*)&Xs[k][lane * 2];
            const float* wr = wb + (size_t)k * FULL;       // uniform, 64B-aligned
#pragma unroll
            for (int j = 0; j < 16; ++j) {
                float w = wr[j];                           // s_load -> SGPR
                acc0[j] = fmaf(a.x, w, acc0[j]);
                acc1[j] = fmaf(a.y, w, acc1[j]);
            }
        }
    }
}

// R'[b][n][t] = sum_d u[b][d][t] * Bqt[d][n]. grid (4,8,32), block 256.
__global__ __launch_bounds__(256, 4) void gemm_R(const float* __restrict__ u,
                                                 const float* __restrict__ Bqt,
                                                 float* __restrict__ Rp) {
    __shared__ float Xs[16][128];
    const int b  = blockIdx.z;
    const int t0 = blockIdx.x * 128, n0 = blockIdx.y * 64;
    const int tid = threadIdx.x, lane = tid & 63;
    const int wave = __builtin_amdgcn_readfirstlane(tid >> 6);
    const int nw0 = n0 + wave * 16;
    float acc0[16] = {}, acc1[16] = {};
    gemm_pass_sgpr(u + (size_t)b * (FULL * FULL), Bqt, t0, nw0, acc0, acc1, Xs, tid, lane);
    float* Rb = Rp + (size_t)b * (FULL * FULL);
#pragma unroll
    for (int j = 0; j < 16; ++j) {
        float2 v = make_float2(acc0[j], acc1[j]);
        *(float2*)(Rb + (size_t)(nw0 + j) * FULL + t0 + lane * 2) = v;
    }
}

// Per-(b,n) recurrence (bitwise np: mul-then-add, q8), pure row scan.
// R'[b][n][t] -> S[b][n][t]. grid (32,4), block 128.
__global__ __launch_bounds__(128) void recur(const float* __restrict__ Rp,
                                             const float* __restrict__ Aq,
                                             float* __restrict__ S) {
    const int b = blockIdx.x;
    const int n = blockIdx.y * 128 + threadIdx.x;
    const float a = Aq[n];
    const float* r = Rp + (size_t)b * (FULL * FULL) + (size_t)n * FULL;
    float* s = S + (size_t)b * (FULL * FULL) + (size_t)n * FULL;
    float st = 0.0f;
    for (int t = 0; t < FULL; t += 4) {
        float4 rv = *(const float4*)(r + t);
        float4 ov;
        st = q8(__fadd_rn(__fmul_rn(st, a), rv.x)); ov.x = st;
        st = q8(__fadd_rn(__fmul_rn(st, a), rv.y)); ov.y = st;
        st = q8(__fadd_rn(__fmul_rn(st, a), rv.z)); ov.z = st;
        st = q8(__fadd_rn(__fmul_rn(st, a), rv.w)); ov.w = st;
        *(float4*)(s + t) = ov;
    }
}

// Y[b][o][t] = q8( (sum_n S[n][t]*Cqt[n][o]) + (sum_d u[d][t]*Dqt[d][o]) )
// grid (4,8,32), block 256.
__global__ __launch_bounds__(256, 4) void gemm_Y(const float* __restrict__ u,
                                                 const float* __restrict__ S,
                                                 const float* __restrict__ Cqt,
                                                 const float* __restrict__ Dqt,
                                                 float* __restrict__ Y) {
    __shared__ float Xs[16][128];
    const int b  = blockIdx.z;
    const int t0 = blockIdx.x * 128, o0 = blockIdx.y * 64;
    const int tid = threadIdx.x, lane = tid & 63;
    const int wave = __builtin_amdgcn_readfirstlane(tid >> 6);
    const int ow0 = o0 + wave * 16;
    float c0[16] = {}, c1[16] = {};
    gemm_pass_sgpr(S + (size_t)b * (FULL * FULL), Cqt, t0, ow0, c0, c1, Xs, tid, lane);
    float a0[16] = {}, a1[16] = {};
    gemm_pass_sgpr(u + (size_t)b * (FULL * FULL), Dqt, t0, ow0, a0, a1, Xs, tid, lane);
    float* Yb = Y + (size_t)b * (FULL * FULL);
#pragma unroll
    for (int j = 0; j < 16; ++j) {
        float2 v;
        v.x = q8(__fadd_rn(c0[j], a0[j]));
        v.y = q8(__fadd_rn(c1[j], a1[j]));
        *(float2*)(Yb + (size_t)(ow0 + j) * FULL + t0 + lane * 2) = v;
    }
}

extern "C" void kernel_launch(void* const* d_in, const int* in_sizes, int n_in,
                              void* d_out, int out_size, void* d_ws, size_t ws_size,
                              hipStream_t stream) {
    const float* u = (const float*)d_in[0];   // (32, 512, 512)
    const float* A = (const float*)d_in[1];   // (512,)
    const float* B = (const float*)d_in[2];   // (512, 512)
    const float* C = (const float*)d_in[3];   // (512, 512)
    const float* D = (const float*)d_in[4];   // (512, 512)

    float* ws  = (float*)d_ws;
    float* Aq  = ws;                    // 512
    float* Bqt = Aq + 512;              // 262144  [d][n]
    float* Cqt = Bqt + 262144;          // 262144  [n][o]
    float* Dqt = Cqt + 262144;          // 262144  [d][o]
    float* Rp  = Dqt + 262144;          // 8388608 [b][n][t]
    float* S   = Rp + 8388608;          // 8388608 [b][n][t]
    float* Y   = (float*)d_out;         // 8388608 [b][o][t]

    quantk<<<2, 256, 0, stream>>>(A, Aq, 512);
    quantT3<<<dim3(16, 16, 3), 256, 0, stream>>>(B, C, D, Bqt, Cqt, Dqt);

    gemm_R<<<dim3(4, 8, 32), 256, 0, stream>>>(u, Bqt, Rp);
    recur<<<dim3(32, 4), 128, 0, stream>>>(Rp, Aq, S);
    gemm_Y<<<dim3(4, 8, 32), 256, 0, stream>>>(u, S, Cqt, Dqt, Y);
}

// Round 8
// 470.394 us; speedup vs baseline: 1.5774x; 1.0437x over previous
//
#include <hip/hip_runtime.h>
#include <hip/hip_bf16.h>

// QuantizedSimpleSSM — round 8: wave-strip GEMM with W via LDS broadcast.
// R7's SGPR scheme stalled on lgkmcnt(0) drains (SMEM returns out-of-order).
// Here W comes from a small LDS tile read at wave-uniform addresses (HW
// broadcast, conflict-free), X via per-lane ds_read_b64. Per k per lane:
// 32 FMA vs 5 LDS instructions -> ~90% VALU-issue ceiling.
// Block 256 (4 waves), tile 128(t) x 64(n), grid 1024 = 4 blocks/CU.
// Numerics contract (absmax 0.0 since R2): every output element is one fp32
// FMA chain in strictly ascending k; recurrence mul-then-add + q8. Unchanged.

#define FULL 512

__device__ __forceinline__ float q8(float x) {
    float xa = fabsf(x);
    float w  = __fadd_rn(xa, 1e-8f);
    int e = (int)((__float_as_uint(w) >> 23) & 0xFFu) - 127;   // floor(log2(w))
    e = e < -7 ? -7 : (e > 7 ? 7 : e);
    float p    = __int_as_float((unsigned)((e + 127) << 23));   // exact 2^e
    float invp = __int_as_float((unsigned)((127 - e) << 23));   // exact 2^-e
    float t  = __fmul_rn(__fsub_rn(__fmul_rn(xa, invp), 1.0f), 8.0f);
    float m  = __fmul_rn(rintf(t), 0.125f);                     // half-to-even
    float r  = __fmul_rn(__fadd_rn(1.0f, m), p);
    return copysignf(r, x);
}

__global__ void quantk(const float* __restrict__ in, float* __restrict__ out, int n) {
    int i = blockIdx.x * blockDim.x + threadIdx.x;
    if (i < n) out[i] = q8(in[i]);
}

// out[c][r] = q8(in[r][c]) for three 512x512 matrices. grid (16,16,3), block 256.
__global__ __launch_bounds__(256) void quantT3(const float* __restrict__ B,
                                               const float* __restrict__ C,
                                               const float* __restrict__ D,
                                               float* __restrict__ Bqt,
                                               float* __restrict__ Cqt,
                                               float* __restrict__ Dqt) {
    __shared__ float tl[32][33];
    const float* in = blockIdx.z == 0 ? B : (blockIdx.z == 1 ? C : D);
    float* out      = blockIdx.z == 0 ? Bqt : (blockIdx.z == 1 ? Cqt : Dqt);
    const int r0 = blockIdx.y * 32, c0 = blockIdx.x * 32;
    const int x = threadIdx.x & 31, y = threadIdx.x >> 5;   // 32 x 8
#pragma unroll
    for (int i = 0; i < 32; i += 8)
        tl[y + i][x] = q8(in[(r0 + y + i) * FULL + c0 + x]);
    __syncthreads();
#pragma unroll
    for (int i = 0; i < 32; i += 8)
        out[(c0 + y + i) * FULL + r0 + x] = tl[x][y + i];
}

// acc0[j]/acc1[j] accumulate Out[m0+lane*2+{0,1}][n0+wv*16+j] over k ascending.
// X, Wt are [512][512] row-major (Wt = transposed weight: Wt[k][n]).
// Xs[16][128] per-lane; Ws[16][64] read at wave-uniform addresses (broadcast).
__device__ __forceinline__ void gemm_pass_bcast(const float* __restrict__ X,
                                                const float* __restrict__ Wt,
                                                int m0, int n0,
                                                float (&acc0)[16], float (&acc1)[16],
                                                float (*Xs)[128], float (*Ws)[64],
                                                int tid, int lane, int nw) {
    const int xrow = tid >> 4, xcol = (tid & 15) * 8;   // 16 x (16*8) staging
    const int wcol = (tid & 15) * 4;                    // 16 x (16*4) staging
    const float* xp = X  + (size_t)xrow * FULL + m0 + xcol;
    const float* wp = Wt + (size_t)xrow * FULL + n0 + wcol;
    for (int k0 = 0; k0 < FULL; k0 += 16) {
        float4 x0 = *(const float4*)xp;
        float4 x1 = *(const float4*)(xp + 4);
        float4 w0 = *(const float4*)wp;
        xp += 16 * FULL; wp += 16 * FULL;
        __syncthreads();                 // prev compute done reading LDS
        *(float4*)&Xs[xrow][xcol]     = x0;
        *(float4*)&Xs[xrow][xcol + 4] = x1;
        *(float4*)&Ws[xrow][wcol]     = w0;
        __syncthreads();
#pragma unroll
        for (int k = 0; k < 16; ++k) {
            float2 a = *(const float2*)&Xs[k][lane * 2];
            float w[16];
            *(float4*)&w[0]  = *(const float4*)&Ws[k][nw];       // broadcast
            *(float4*)&w[4]  = *(const float4*)&Ws[k][nw + 4];
            *(float4*)&w[8]  = *(const float4*)&Ws[k][nw + 8];
            *(float4*)&w[12] = *(const float4*)&Ws[k][nw + 12];
#pragma unroll
            for (int j = 0; j < 16; ++j) {
                acc0[j] = fmaf(a.x, w[j], acc0[j]);
                acc1[j] = fmaf(a.y, w[j], acc1[j]);
            }
        }
    }
}

// R'[b][n][t] = sum_d u[b][d][t] * Bqt[d][n]. grid (4,8,32), block 256.
__global__ __launch_bounds__(256, 4) void gemm_R(const float* __restrict__ u,
                                                 const float* __restrict__ Bqt,
                                                 float* __restrict__ Rp) {
    __shared__ float Xs[16][128];
    __shared__ float Ws[16][64];
    const int b  = blockIdx.z;
    const int t0 = blockIdx.x * 128, n0 = blockIdx.y * 64;
    const int tid = threadIdx.x, lane = tid & 63;
    const int nw = __builtin_amdgcn_readfirstlane((tid >> 6) * 16);
    float acc0[16] = {}, acc1[16] = {};
    gemm_pass_bcast(u + (size_t)b * (FULL * FULL), Bqt, t0, n0,
                    acc0, acc1, Xs, Ws, tid, lane, nw);
    float* Rb = Rp + (size_t)b * (FULL * FULL);
#pragma unroll
    for (int j = 0; j < 16; ++j) {
        float2 v = make_float2(acc0[j], acc1[j]);
        *(float2*)(Rb + (size_t)(n0 + nw + j) * FULL + t0 + lane * 2) = v;
    }
}

// Per-(b,n) recurrence (bitwise np: mul-then-add, q8), pure row scan.
// R'[b][n][t] -> S[b][n][t]. grid (32,4), block 128.
__global__ __launch_bounds__(128) void recur(const float* __restrict__ Rp,
                                             const float* __restrict__ Aq,
                                             float* __restrict__ S) {
    const int b = blockIdx.x;
    const int n = blockIdx.y * 128 + threadIdx.x;
    const float a = Aq[n];
    const float* r = Rp + (size_t)b * (FULL * FULL) + (size_t)n * FULL;
    float* s = S + (size_t)b * (FULL * FULL) + (size_t)n * FULL;
    float st = 0.0f;
    for (int t = 0; t < FULL; t += 4) {
        float4 rv = *(const float4*)(r + t);
        float4 ov;
        st = q8(__fadd_rn(__fmul_rn(st, a), rv.x)); ov.x = st;
        st = q8(__fadd_rn(__fmul_rn(st, a), rv.y)); ov.y = st;
        st = q8(__fadd_rn(__fmul_rn(st, a), rv.z)); ov.z = st;
        st = q8(__fadd_rn(__fmul_rn(st, a), rv.w)); ov.w = st;
        *(float4*)(s + t) = ov;
    }
}

// Y[b][o][t] = q8( (sum_n S[n][t]*Cqt[n][o]) + (sum_d u[d][t]*Dqt[d][o]) )
// grid (4,8,32), block 256.
__global__ __launch_bounds__(256, 4) void gemm_Y(const float* __restrict__ u,
                                                 const float* __restrict__ S,
                                                 const float* __restrict__ Cqt,
                                                 const float* __restrict__ Dqt,
                                                 float* __restrict__ Y) {
    __shared__ float Xs[16][128];
    __shared__ float Ws[16][64];
    const int b  = blockIdx.z;
    const int t0 = blockIdx.x * 128, o0 = blockIdx.y * 64;
    const int tid = threadIdx.x, lane = tid & 63;
    const int nw = __builtin_amdgcn_readfirstlane((tid >> 6) * 16);
    float c0[16] = {}, c1[16] = {};
    gemm_pass_bcast(S + (size_t)b * (FULL * FULL), Cqt, t0, o0,
                    c0, c1, Xs, Ws, tid, lane, nw);
    float a0[16] = {}, a1[16] = {};
    gemm_pass_bcast(u + (size_t)b * (FULL * FULL), Dqt, t0, o0,
                    a0, a1, Xs, Ws, tid, lane, nw);
    float* Yb = Y + (size_t)b * (FULL * FULL);
#pragma unroll
    for (int j = 0; j < 16; ++j) {
        float2 v;
        v.x = q8(__fadd_rn(c0[j], a0[j]));
        v.y = q8(__fadd_rn(c1[j], a1[j]));
        *(float2*)(Yb + (size_t)(o0 + nw + j) * FULL + t0 + lane * 2) = v;
    }
}

extern "C" void kernel_launch(void* const* d_in, const int* in_sizes, int n_in,
                              void* d_out, int out_size, void* d_ws, size_t ws_size,
                              hipStream_t stream) {
    const float* u = (const float*)d_in[0];   // (32, 512, 512)
    const float* A = (const float*)d_in[1];   // (512,)
    const float* B = (const float*)d_in[2];   // (512, 512)
    const float* C = (const float*)d_in[3];   // (512, 512)
    const float* D = (const float*)d_in[4];   // (512, 512)

    float* ws  = (float*)d_ws;
    float* Aq  = ws;                    // 512
    float* Bqt = Aq + 512;              // 262144  [d][n]
    float* Cqt = Bqt + 262144;          // 262144  [n][o]
    float* Dqt = Cqt + 262144;          // 262144  [d][o]
    float* Rp  = Dqt + 262144;          // 8388608 [b][n][t]
    float* S   = Rp + 8388608;          // 8388608 [b][n][t]
    float* Y   = (float*)d_out;         // 8388608 [b][o][t]

    quantk<<<2, 256, 0, stream>>>(A, Aq, 512);
    quantT3<<<dim3(16, 16, 3), 256, 0, stream>>>(B, C, D, Bqt, Cqt, Dqt);

    gemm_R<<<dim3(4, 8, 32), 256, 0, stream>>>(u, Bqt, Rp);
    recur<<<dim3(32, 4), 128, 0, stream>>>(Rp, Aq, S);
    gemm_Y<<<dim3(4, 8, 32), 256, 0, stream>>>(u, S, Cqt, Dqt, Y);
}